// Round 1
// baseline (714.031 us; speedup 1.0000x reference)
//
#include <hip/hip_runtime.h>
#include <hip/hip_cooperative_groups.h>
#include <math.h>

namespace cg = cooperative_groups;

#define BB 8
#define SS 512
#define DDIM 1024
#define NBLK 256

struct Params {
    const float *x, *w_v, *b_v, *w_o, *b_o;
    const float *aw1, *ab1, *aw2, *ab2, *vqc, *pw1, *pb1, *pw2, *pb2;
    const float *mew1, *meb1, *mew2, *meb2, *mst;
    const float *rw1, *rb1, *rw2, *rb2;
    const float *brw1, *brb1, *brw2, *brb2;
    const float *lnsc, *lnof;
    float* ws;
    float4* out;
};

// One matvec stage: identical decomposition/arithmetic order to the previous
// standalone mv2_k (32 output cols x KR k-slice per task, 8 batches).
// in_parts: [NP][8][K] partial slices (summed at staging, premul+ACT applied),
// out_part: [K/KR][8][DOUT] partial slices.  ACT: 0=id 1=tanh 2=silu 3=vqc-scale
template <int ACT, int NP, int KR, int K, int DOUT>
__device__ __forceinline__ void mv2_stage(const float* __restrict__ in_parts,
                                          const float* __restrict__ W,
                                          const float* __restrict__ bias,
                                          float* __restrict__ out_part,
                                          const float* __restrict__ vqc,
                                          float premul, int task,
                                          float* __restrict__ sin_,
                                          float* __restrict__ red) {
    constexpr int NI  = KR / 128;      // float4 staging positions per thread
    constexpr int NJB = DOUT / 32;     // j-blocks
    const int t  = threadIdx.x;
    const int jb = task % NJB;
    const int kb = task / NJB;
    const int j0 = jb * 32;
    const int k0 = kb * KR;

    // ---- staging: sum NP partials, premul, activation, into LDS [b][k] ----
#pragma unroll
    for (int i = 0; i < NI; ++i) {
        int f  = i * 256 + t;                 // < 8*KR/4
        int b  = f / (KR / 4);
        int kq = f % (KR / 4);
        const float* src = in_parts + (size_t)b * K + k0 + kq * 4;
        float4 v = make_float4(0.f, 0.f, 0.f, 0.f);
#pragma unroll
        for (int pq = 0; pq < NP; ++pq) {
            float4 u = *(const float4*)(src + (size_t)pq * 8 * K);
            v.x += u.x; v.y += u.y; v.z += u.z; v.w += u.w;
        }
        float vv[4] = {v.x * premul, v.y * premul, v.z * premul, v.w * premul};
#pragma unroll
        for (int c = 0; c < 4; ++c) {
            float s = vv[c];
            if (ACT == 1) {
                s = tanhf(s);
            } else if (ACT == 2) {
                s = s / (1.f + expf(-s));
            } else if (ACT == 3) {
                int kk = k0 + kq * 4 + c;
                float th = vqc[(size_t)kk * 4 + 0] * 0.5f;
                float ph = vqc[(size_t)kk * 4 + 1];
                s *= (cosf(th) + sinf(th) * cosf(ph));
            }
            vv[c] = s;
        }
        *(float4*)&sin_[b * KR + kq * 4] = make_float4(vv[0], vv[1], vv[2], vv[3]);
    }
    __syncthreads();

    // ---- compute: thread (kg, jq): 4 j-columns x 8 batches over NI*4 k's ----
    const int jq = t & 7, kg = t >> 3;
    float acc[8][4];
#pragma unroll
    for (int b = 0; b < 8; ++b)
#pragma unroll
        for (int c = 0; c < 4; ++c) acc[b][c] = 0.f;
#pragma unroll
    for (int i = 0; i < NI; ++i) {
#pragma unroll
        for (int c = 0; c < 4; ++c) {
            int kl = kg * (NI * 4) + i * 4 + c;
            float4 w4 = *(const float4*)(W + (size_t)(k0 + kl) * DOUT + j0 + jq * 4);
#pragma unroll
            for (int b = 0; b < 8; ++b) {
                float s = sin_[b * KR + kl];
                acc[b][0] += s * w4.x; acc[b][1] += s * w4.y;
                acc[b][2] += s * w4.z; acc[b][3] += s * w4.w;
            }
        }
    }

    // ---- reduce 32 kg-groups via LDS ----
#pragma unroll
    for (int b = 0; b < 8; ++b)
#pragma unroll
        for (int c = 0; c < 4; ++c)
            red[(b * 32 + jq * 4 + c) * 33 + kg] = acc[b][c];
    __syncthreads();
    float s = 0.f;
#pragma unroll
    for (int g = 0; g < 32; ++g) s += red[t * 33 + g];
    const int b = t >> 5, jc = t & 31;
    const int j = j0 + jc;
    if (bias != nullptr && kb == 0) s += bias[j];
    out_part[(size_t)kb * 8 * DOUT + (size_t)b * DOUT + j] = s;
}

__global__ __launch_bounds__(256, 1) void fused_k(Params p) {
    cg::grid_group grid = cg::this_grid();
    __shared__ float sin_[8 * 256];      // 8 KB  (staged activations, max KR=256)
    __shared__ float red[256 * 33];      // 33.8 KB (transpose-reduce; aliased by mem/ln)
    const int t = threadIdx.x;
    const int bid = blockIdx.x;

    float* ws     = p.ws;
    float* xpart  = ws;               // [32][8][1024]  262144
    float* vfullp = ws + 262144;      // [8][8][1024]    65536
    float* yparts = ws + 327680;      // [24][8][1024]  196608 (y0|h0|h1)
    float* t0p    = ws + 524288;      // [8][8][1024]    65536
    float* a0p    = ws + 589824;      // [8][8][1024]    65536
    float* s0p    = ws + 655360;      // [8][8][1024]    65536
    float* maccp  = ws + 720896;      // [8][8][1024]    65536
    float* comb   = ws + 786432;      // [8][2048]       16384
    float* hbap   = ws + 802816;      // [8][8][2048]   131072
    float* hbccp  = ws + 933888;      // [8][8][1024]    65536
    float* y0p = yparts;
    float* h0p = yparts + 65536;
    float* h1p = yparts + 131072;
    const int DDm = DDIM * DDIM;

    // ---------------- stage 1: x row-sums, 32 private slices ----------------
    {
        int b = bid >> 5, sc = bid & 31;
        const float4* x4 = (const float4*)p.x;
        size_t base = ((size_t)b * SS + (size_t)sc * 16) * (DDIM / 4);
        float4 a = make_float4(0.f, 0.f, 0.f, 0.f);
#pragma unroll
        for (int ss = 0; ss < 16; ++ss) {
            float4 v = x4[base + (size_t)ss * (DDIM / 4) + t];
            a.x += v.x; a.y += v.y; a.z += v.z; a.w += v.w;
        }
        ((float4*)xpart)[((size_t)sc * 8 + b) * (DDIM / 4) + t] = a;
    }
    grid.sync();

    // Vmean = (xsum/512) @ w_v + b_v
    mv2_stage<0, 32, 128, 1024, 1024>(xpart, p.w_v, p.b_v, vfullp, nullptr, 1.f / 512.f, bid, sin_, red);
    grid.sync();
    // y0 = Vmean @ w_o + b_o
    mv2_stage<0, 8, 128, 1024, 1024>(vfullp, p.w_o, p.b_o, y0p, nullptr, 1.f, bid, sin_, red);
    grid.sync();
    // quantum layer 0 (y = y0)
    mv2_stage<0, 8, 128, 1024, 1024>(y0p, p.aw1, p.ab1, t0p, nullptr, 1.f, bid, sin_, red);
    grid.sync();
    mv2_stage<1, 8, 128, 1024, 1024>(t0p, p.aw2, p.ab2, a0p, nullptr, 1.f, bid, sin_, red);
    grid.sync();
    mv2_stage<3, 8, 128, 1024, 1024>(a0p, p.pw1, p.pb1, s0p, p.vqc, 1.f, bid, sin_, red);
    grid.sync();
    mv2_stage<2, 8, 128, 1024, 1024>(s0p, p.pw2, p.pb2, h0p, nullptr, 1.f, bid, sin_, red);
    grid.sync();
    // quantum layer 1 (y = y0 + h0 -> NP=16)
    mv2_stage<0, 16, 128, 1024, 1024>(yparts, p.aw1 + DDm, p.ab1 + 1024, t0p, nullptr, 1.f, bid, sin_, red);
    grid.sync();
    mv2_stage<1, 8, 128, 1024, 1024>(t0p, p.aw2 + DDm, p.ab2 + 1024, a0p, nullptr, 1.f, bid, sin_, red);
    grid.sync();
    mv2_stage<3, 8, 128, 1024, 1024>(a0p, p.pw1 + DDm, p.pb1 + 1024, s0p, p.vqc + 4096, 1.f, bid, sin_, red);
    grid.sync();
    mv2_stage<2, 8, 128, 1024, 1024>(s0p, p.pw2 + DDm, p.pb2 + 1024, h1p, nullptr, 1.f, bid, sin_, red);
    grid.sync();
    // memory encoder first matmul (y = y0+h0+h1 -> NP=24)
    mv2_stage<0, 24, 128, 1024, 1024>(yparts, p.mew1, p.meb1, maccp, nullptr, 1.f, bid, sin_, red);
    grid.sync();

    // ---------------- memory retrieval: blocks 0-7 retrieval path,
    // ---------------- blocks 8-15 write the y-half of comb in parallel ------
    if (bid < 8) {
        const int b = bid;
        float* sh_t  = red;                    // 1024
        float* sh_p  = red + 1024;             // 256
        float* sh_mq = red + 1280;             // 16
        float* sh_sc = red + 1296;             // 512
        float* sh_rv = red + 1808;             // 256
        int*   sh_ri = (int*)(red + 2064);     // 256
        float* sh_f1 = red + 2320;             // 24
        float* sh_fb = red + 2344;             // 8
        int*   sh_top = (int*)(red + 2352);    // 3
        for (int i = t; i < DDIM; i += 256) {
            float v = 0.f;
#pragma unroll
            for (int pq = 0; pq < 8; ++pq) v += maccp[(size_t)pq * 8 * DDIM + (size_t)b * DDIM + i];
            sh_t[i] = tanhf(v);
        }
        __syncthreads();
        {   // mq = tanh(macc) @ mew2 + meb2 (16 outputs, 16-way K split)
            int j = t & 15, g = t >> 4;
            float s = 0.f;
            int kbase = g * 64;
            for (int k = 0; k < 64; ++k) s += sh_t[kbase + k] * p.mew2[(size_t)(kbase + k) * 16 + j];
            sh_p[t] = s;
        }
        __syncthreads();
        if (t < 16) {
            float v = 0.f;
            for (int g = 0; g < 16; ++g) v += sh_p[g * 16 + t];
            sh_mq[t] = v + p.meb2[t];
        }
        __syncthreads();
        for (int m = t; m < 512; m += 256) {
            float d = 0.f;
#pragma unroll
            for (int i = 0; i < 16; ++i) d += sh_mq[i] * p.mst[m * 16 + i];
            sh_sc[m] = d * d;
        }
        __syncthreads();
        // top-3 (argsort tail semantics: ties prefer larger index)
        for (int r = 0; r < 3; ++r) {
            float bv = -1.f; int bi = -1;
            for (int m = t; m < 512; m += 256) {
                float v = sh_sc[m];
                if (v > bv || (v == bv && m > bi)) { bv = v; bi = m; }
            }
            sh_rv[t] = bv; sh_ri[t] = bi;
            __syncthreads();
            for (int st = 128; st > 0; st >>= 1) {
                if (t < st) {
                    float v2 = sh_rv[t + st]; int i2 = sh_ri[t + st];
                    if (v2 > sh_rv[t] || (v2 == sh_rv[t] && i2 > sh_ri[t])) { sh_rv[t] = v2; sh_ri[t] = i2; }
                }
                __syncthreads();
            }
            if (t == 0) { sh_top[r] = sh_ri[0]; sh_sc[sh_ri[0]] = -1.f; }
            __syncthreads();
        }
        if (t < 24) {
            int k = t >> 3, i = t & 7;
            int m = sh_top[k];
            float a = p.rb1[i];
#pragma unroll
            for (int ii = 0; ii < 8; ++ii) a += p.mst[m * 16 + ii] * p.rw1[ii * 8 + i];
            sh_f1[k * 8 + i] = tanhf(a);
        }
        __syncthreads();
        if (t < 8) sh_fb[t] = (sh_f1[t] + sh_f1[8 + t] + sh_f1[16 + t]) * (1.f / 3.f);
        __syncthreads();
        for (int jj = t; jj < DDIM; jj += 256) {
            float v = p.rb2[jj];
#pragma unroll
            for (int i = 0; i < 8; ++i) v += sh_fb[i] * p.rw2[(size_t)i * DDIM + jj];
            comb[(size_t)b * 2048 + 1024 + jj] = v;
        }
    } else if (bid < 16) {
        const int b = bid - 8;
        for (int jj = t; jj < DDIM; jj += 256) {
            float y = 0.f;
#pragma unroll
            for (int pq = 0; pq < 24; ++pq) y += yparts[(size_t)pq * 8 * DDIM + (size_t)b * DDIM + jj];
            comb[(size_t)b * 2048 + jj] = y;
        }
    }
    grid.sync();

    // ---------------- bridge MLP ----------------
    // br1: K=2048, Dout=2048 -> 512 tasks over 256 blocks (two tasks each)
    mv2_stage<0, 1, 256, 2048, 2048>(comb, p.brw1, p.brb1, hbap, nullptr, 1.f, bid, sin_, red);
    mv2_stage<0, 1, 256, 2048, 2048>(comb, p.brw1, p.brb1, hbap, nullptr, 1.f, bid + 256, sin_, red);
    grid.sync();
    mv2_stage<2, 8, 256, 2048, 1024>(hbap, p.brw2, p.brb2, hbccp, nullptr, 1.f, bid, sin_, red);
    grid.sync();

    // ---------------- layernorm (redundant per block) + broadcast ----------
    {
        const int b = bid >> 5;            // 32 blocks share each batch row
        float* sh_v = red;                 // 1024
        float* rs = red + 1024;            // 256
        float* rq = red + 1280;            // 256
        float s = 0.f, q = 0.f;
        for (int i = t; i < DDIM; i += 256) {
            float v = 0.f;
#pragma unroll
            for (int pq = 0; pq < 8; ++pq) v += hbccp[(size_t)pq * 8 * DDIM + (size_t)b * DDIM + i];
            sh_v[i] = v;
            s += v; q += v * v;
        }
        rs[t] = s; rq[t] = q;
        __syncthreads();
        for (int st = 128; st > 0; st >>= 1) {
            if (t < st) { rs[t] += rs[t + st]; rq[t] += rq[t + st]; }
            __syncthreads();
        }
        float mu  = rs[0] * (1.f / DDIM);
        float var = rq[0] * (1.f / DDIM) - mu * mu;
        var = var < 0.f ? 0.f : var;
        float inv = 1.f / sqrtf(var + 1e-5f);
        for (int i = t; i < DDIM; i += 256)
            sh_v[i] = (sh_v[i] - mu) * inv * p.lnsc[i] + p.lnof[i];
        __syncthreads();
        // each block writes its 16 s-rows slice; thread t always owns column t
        const float4 myv = ((const float4*)sh_v)[t];
#pragma unroll
        for (int k = 0; k < 16; ++k) {
            unsigned f = (unsigned)bid * 4096u + (unsigned)k * 256u + t;
            p.out[f] = myv;
        }
    }
}

extern "C" void kernel_launch(void* const* d_in, const int* in_sizes, int n_in,
                              void* d_out, int out_size, void* d_ws, size_t ws_size,
                              hipStream_t stream) {
    Params p;
    p.x    = (const float*)d_in[0];
    p.w_v  = (const float*)d_in[5];
    p.b_v  = (const float*)d_in[6];
    p.w_o  = (const float*)d_in[7];
    p.b_o  = (const float*)d_in[8];
    p.aw1  = (const float*)d_in[15];
    p.ab1  = (const float*)d_in[16];
    p.aw2  = (const float*)d_in[17];
    p.ab2  = (const float*)d_in[18];
    p.vqc  = (const float*)d_in[19];
    p.pw1  = (const float*)d_in[20];
    p.pb1  = (const float*)d_in[21];
    p.pw2  = (const float*)d_in[22];
    p.pb2  = (const float*)d_in[23];
    p.mew1 = (const float*)d_in[24];
    p.meb1 = (const float*)d_in[25];
    p.mew2 = (const float*)d_in[26];
    p.meb2 = (const float*)d_in[27];
    p.mst  = (const float*)d_in[28];
    p.rw1  = (const float*)d_in[29];
    p.rb1  = (const float*)d_in[30];
    p.rw2  = (const float*)d_in[31];
    p.rb2  = (const float*)d_in[32];
    p.brw1 = (const float*)d_in[33];
    p.brb1 = (const float*)d_in[34];
    p.brw2 = (const float*)d_in[35];
    p.brb2 = (const float*)d_in[36];
    p.lnsc = (const float*)d_in[37];
    p.lnof = (const float*)d_in[38];
    p.ws   = (float*)d_ws;
    p.out  = (float4*)d_out;

    void* args[] = { (void*)&p };
    hipLaunchCooperativeKernel((const void*)fused_k, dim3(NBLK), dim3(256), args, 0, stream);
}

// Round 2
// 259.835 us; speedup vs baseline: 2.7480x; 2.7480x over previous
//
#include <hip/hip_runtime.h>
#include <math.h>

#define BB 8
#define SS 512
#define DDIM 1024

// ---------------- x sum over S, non-atomic: 32 private partial slices ----------------
// grid: 256 blocks = B(8) x 32 s-chunks of 16 rows; block 256 (one float4 of D each)
// xpart layout: [32][8][1024]
__global__ __launch_bounds__(256) void xsum_k(const float* __restrict__ x,
                                              float* __restrict__ xpart) {
    int b  = blockIdx.x >> 5;
    int sc = blockIdx.x & 31;
    int t  = threadIdx.x;
    const float4* x4 = (const float4*)x;
    size_t base = ((size_t)b * SS + (size_t)sc * 16) * (DDIM / 4);
    float4 a = make_float4(0.f, 0.f, 0.f, 0.f);
#pragma unroll
    for (int ss = 0; ss < 16; ++ss) {
        float4 v = x4[base + (size_t)ss * (DDIM / 4) + t];
        a.x += v.x; a.y += v.y; a.z += v.z; a.w += v.w;
    }
    ((float4*)xpart)[((size_t)sc * 8 + b) * (DDIM / 4) + t] = a;
}

// ---------------- batch-8 vec-mat, atomic-free split-K with private partial slices ----
// in_parts: [NP][8][K] (summed at staging), out_part: [8][8][Dout] (slice blockIdx.y)
// staged value = ACT( premul * sum_p in_parts[p][b][k] ); bias added at ky==0.
// ACT: 0=identity 1=tanh 2=silu 3=*quantum-scale(vqc)
// grid: (Dout/32, 8); block 256. KR = K/8 (128 or 256).
template <int ACT, int NP, int KR>
__global__ __launch_bounds__(256) void mv2_k(const float* __restrict__ in_parts,
                                             const float* __restrict__ W,
                                             const float* __restrict__ bias,
                                             float* __restrict__ out_part,
                                             const float* __restrict__ vqc,
                                             float premul, int K, int Dout) {
    constexpr int NI = KR / 128;             // float4 staging positions per thread
    __shared__ float sin_[8 * KR];           // [b][KR]
    __shared__ float red[256 * 33];          // [out 256][kg 32 +pad]
    int t  = threadIdx.x;
    int j0 = blockIdx.x * 32;
    int k0 = blockIdx.y * KR;

    // ---- staging: sum NP partials, premul, activation, into LDS [b][k] ----
#pragma unroll
    for (int i = 0; i < NI; ++i) {
        int f  = i * 256 + t;                // < 8*KR/4
        int b  = f / (KR / 4);
        int kq = f % (KR / 4);
        const float* src = in_parts + (size_t)b * K + k0 + kq * 4;
        float4 v = make_float4(0.f, 0.f, 0.f, 0.f);
#pragma unroll
        for (int p = 0; p < NP; ++p) {
            float4 u = *(const float4*)(src + (size_t)p * 8 * K);
            v.x += u.x; v.y += u.y; v.z += u.z; v.w += u.w;
        }
        float vv[4] = {v.x * premul, v.y * premul, v.z * premul, v.w * premul};
#pragma unroll
        for (int c = 0; c < 4; ++c) {
            float s = vv[c];
            if (ACT == 1) {
                s = tanhf(s);
            } else if (ACT == 2) {
                s = s / (1.f + expf(-s));
            } else if (ACT == 3) {
                int kk = k0 + kq * 4 + c;
                float th = vqc[(size_t)kk * 4 + 0] * 0.5f;
                float ph = vqc[(size_t)kk * 4 + 1];
                s *= (cosf(th) + sinf(th) * cosf(ph));
            }
            vv[c] = s;
        }
        *(float4*)&sin_[b * KR + kq * 4] = make_float4(vv[0], vv[1], vv[2], vv[3]);
    }
    __syncthreads();

    // ---- compute: thread (kg, jq): 4 j-columns x 8 batches over NI*4 k's ----
    int jq = t & 7, kg = t >> 3;
    float acc[8][4];
#pragma unroll
    for (int b = 0; b < 8; ++b)
#pragma unroll
        for (int c = 0; c < 4; ++c) acc[b][c] = 0.f;
#pragma unroll
    for (int i = 0; i < NI; ++i) {
#pragma unroll
        for (int c = 0; c < 4; ++c) {
            int kl = kg * (NI * 4) + i * 4 + c;
            float4 w4 = *(const float4*)(W + (size_t)(k0 + kl) * Dout + j0 + jq * 4);
#pragma unroll
            for (int b = 0; b < 8; ++b) {
                float s = sin_[b * KR + kl];
                acc[b][0] += s * w4.x; acc[b][1] += s * w4.y;
                acc[b][2] += s * w4.z; acc[b][3] += s * w4.w;
            }
        }
    }

    // ---- reduce 32 kg-groups via LDS ----
#pragma unroll
    for (int b = 0; b < 8; ++b)
#pragma unroll
        for (int c = 0; c < 4; ++c)
            red[(b * 32 + jq * 4 + c) * 33 + kg] = acc[b][c];
    __syncthreads();
    // thread t handles output o = t = b*32 + jc
    float s = 0.f;
#pragma unroll
    for (int g = 0; g < 32; ++g) s += red[t * 33 + g];
    int b = t >> 5, jc = t & 31;
    int j = j0 + jc;
    if (bias != nullptr && blockIdx.y == 0) s += bias[j];
    out_part[(size_t)blockIdx.y * 8 * Dout + (size_t)b * Dout + j] = s;
}

// ---------------- memory retrieval stage (one block per batch row) ----------------
// maccp: [8][8][1024] partials; yparts: [24][8][1024] partials (y = sum of 24)
__global__ __launch_bounds__(256) void mem_k(const float* __restrict__ maccp,
                      const float* __restrict__ mew2,
                      const float* __restrict__ meb2, const float* __restrict__ mem_states,
                      const float* __restrict__ ret_w1, const float* __restrict__ ret_b1,
                      const float* __restrict__ ret_w2, const float* __restrict__ ret_b2,
                      const float* __restrict__ yparts, float* __restrict__ comb) {
    __shared__ float sh_t[DDIM];
    __shared__ float sh_p[256];
    __shared__ float sh_mq[16];
    __shared__ float sh_sc[512];
    __shared__ float sh_rv[256];
    __shared__ int   sh_ri[256];
    __shared__ float sh_f1[24];
    __shared__ float sh_fb[8];
    __shared__ int   sh_top[3];
    int b = blockIdx.x, t = threadIdx.x;
    for (int i = t; i < DDIM; i += 256) {
        float v = 0.f;
#pragma unroll
        for (int p = 0; p < 8; ++p) v += maccp[(size_t)p * 8 * DDIM + (size_t)b * DDIM + i];
        sh_t[i] = tanhf(v);
    }
    __syncthreads();
    {   // mq = tanh(macc) @ mew2 + meb2   (16 outputs, 16-way K split)
        int j = t & 15, g = t >> 4;
        float s = 0.f;
        int kbase = g * 64;
        for (int k = 0; k < 64; ++k) s += sh_t[kbase + k] * mew2[(size_t)(kbase + k) * 16 + j];
        sh_p[t] = s;
    }
    __syncthreads();
    if (t < 16) {
        float v = 0.f;
        for (int g = 0; g < 16; ++g) v += sh_p[g * 16 + t];
        sh_mq[t] = v + meb2[t];
    }
    __syncthreads();
    // scores = (mq . mem_states[m])^2  (softmax monotone -> skip)
    for (int m = t; m < 512; m += 256) {
        float d = 0.f;
#pragma unroll
        for (int i = 0; i < 16; ++i) d += sh_mq[i] * mem_states[m * 16 + i];
        sh_sc[m] = d * d;
    }
    __syncthreads();
    // top-3 (argsort tail: ties prefer larger index)
    for (int r = 0; r < 3; ++r) {
        float bv = -1.f; int bi = -1;
        for (int m = t; m < 512; m += 256) {
            float v = sh_sc[m];
            if (v > bv || (v == bv && m > bi)) { bv = v; bi = m; }
        }
        sh_rv[t] = bv; sh_ri[t] = bi;
        __syncthreads();
        for (int st = 128; st > 0; st >>= 1) {
            if (t < st) {
                float v2 = sh_rv[t + st]; int i2 = sh_ri[t + st];
                if (v2 > sh_rv[t] || (v2 == sh_rv[t] && i2 > sh_ri[t])) { sh_rv[t] = v2; sh_ri[t] = i2; }
            }
            __syncthreads();
        }
        if (t == 0) { sh_top[r] = sh_ri[0]; sh_sc[sh_ri[0]] = -1.f; }
        __syncthreads();
    }
    if (t < 24) {
        int k = t >> 3, i = t & 7;
        int m = sh_top[k];
        float a = ret_b1[i];
#pragma unroll
        for (int ii = 0; ii < 8; ++ii) a += mem_states[m * 16 + ii] * ret_w1[ii * 8 + i];
        sh_f1[k * 8 + i] = tanhf(a);
    }
    __syncthreads();
    if (t < 8) sh_fb[t] = (sh_f1[t] + sh_f1[8 + t] + sh_f1[16 + t]) * (1.f / 3.f);
    __syncthreads();
    // comb = [y, mem_ctx]
    for (int jj = t; jj < DDIM; jj += 256) {
        float v = ret_b2[jj];
#pragma unroll
        for (int i = 0; i < 8; ++i) v += sh_fb[i] * ret_w2[(size_t)i * DDIM + jj];
        comb[(size_t)b * 2048 + 1024 + jj] = v;
        float y = 0.f;
#pragma unroll
        for (int p = 0; p < 24; ++p) y += yparts[(size_t)p * 8 * DDIM + (size_t)b * DDIM + jj];
        comb[(size_t)b * 2048 + jj] = y;
    }
}

// ---------------- fused layernorm + broadcast ----------------
// 256 blocks: block = (b = bid>>5, lb = bid&31). Each block redundantly computes the
// LayerNorm of its batch row (identical reduction order to the old ln_k) and writes
// its 16 s-rows of the (B,S,D) output directly — removes one kernel + row round-trip.
__global__ __launch_bounds__(256) void lnb_k(const float* __restrict__ hbp,
                                             const float* __restrict__ sc,
                                             const float* __restrict__ of,
                                             float4* __restrict__ out) {
    __shared__ float sh_v[DDIM];
    __shared__ float rs[256], rq[256];
    int b = blockIdx.x >> 5, lb = blockIdx.x & 31, t = threadIdx.x;
    float s = 0.f, q = 0.f;
    for (int i = t; i < DDIM; i += 256) {
        float v = 0.f;
#pragma unroll
        for (int p = 0; p < 8; ++p) v += hbp[(size_t)p * 8 * DDIM + (size_t)b * DDIM + i];
        sh_v[i] = v;
        s += v; q += v * v;
    }
    rs[t] = s; rq[t] = q;
    __syncthreads();
    for (int st = 128; st > 0; st >>= 1) {
        if (t < st) { rs[t] += rs[t + st]; rq[t] += rq[t + st]; }
        __syncthreads();
    }
    float mu  = rs[0] * (1.f / DDIM);
    float var = rq[0] * (1.f / DDIM) - mu * mu;
    var = var < 0.f ? 0.f : var;
    float inv = 1.f / sqrtf(var + 1e-5f);
    for (int i = t; i < DDIM; i += 256)
        sh_v[i] = (sh_v[i] - mu) * inv * sc[i] + of[i];
    __syncthreads();
    // thread t owns float4-column t of D; write 16 s-rows
    const float4 myv = ((const float4*)sh_v)[t];
    size_t base = ((size_t)b * SS + (size_t)lb * 16) * (DDIM / 4);
#pragma unroll
    for (int r = 0; r < 16; ++r) {
        out[base + (size_t)r * (DDIM / 4) + t] = myv;
    }
}

extern "C" void kernel_launch(void* const* d_in, const int* in_sizes, int n_in,
                              void* d_out, int out_size, void* d_ws, size_t ws_size,
                              hipStream_t stream) {
    const float* x      = (const float*)d_in[0];
    const float* w_v    = (const float*)d_in[5];
    const float* b_v    = (const float*)d_in[6];
    const float* w_o    = (const float*)d_in[7];
    const float* b_o    = (const float*)d_in[8];
    const float* aw1    = (const float*)d_in[15];
    const float* ab1    = (const float*)d_in[16];
    const float* aw2    = (const float*)d_in[17];
    const float* ab2    = (const float*)d_in[18];
    const float* vqc    = (const float*)d_in[19];
    const float* pw1    = (const float*)d_in[20];
    const float* pb1    = (const float*)d_in[21];
    const float* pw2    = (const float*)d_in[22];
    const float* pb2    = (const float*)d_in[23];
    const float* mew1   = (const float*)d_in[24];
    const float* meb1   = (const float*)d_in[25];
    const float* mew2   = (const float*)d_in[26];
    const float* meb2   = (const float*)d_in[27];
    const float* mst    = (const float*)d_in[28];
    const float* rw1    = (const float*)d_in[29];
    const float* rb1    = (const float*)d_in[30];
    const float* rw2    = (const float*)d_in[31];
    const float* rb2    = (const float*)d_in[32];
    const float* brw1   = (const float*)d_in[33];
    const float* brb1   = (const float*)d_in[34];
    const float* brw2   = (const float*)d_in[35];
    const float* brb2   = (const float*)d_in[36];
    const float* lnsc   = (const float*)d_in[37];
    const float* lnof   = (const float*)d_in[38];

    float* ws     = (float*)d_ws;
    float* xpart  = ws;               // [32][8][1024]  262144
    float* vfullp = ws + 262144;      // [8][8][1024]    65536
    float* yparts = ws + 327680;      // [24][8][1024]  196608 (y0|h0|h1)
    float* t0p    = ws + 524288;      // [8][8][1024]    65536 (reused l0/l1)
    float* a0p    = ws + 589824;      // [8][8][1024]    65536
    float* s0p    = ws + 655360;      // [8][8][1024]    65536
    float* maccp  = ws + 720896;      // [8][8][1024]    65536
    float* comb   = ws + 786432;      // [8][2048]       16384
    float* hbap   = ws + 802816;      // [8][8][2048]   131072
    float* hbccp  = ws + 933888;      // [8][8][1024]    65536

    float* y0p = yparts;
    float* h0p = yparts + 65536;
    float* h1p = yparts + 131072;
    const int DDm = DDIM * DDIM;

    // x row-sums, 32 private slices
    xsum_k<<<256, 256, 0, stream>>>(x, xpart);

    dim3 g1(32, 8);   // Dout=1024, K=1024, KR=128
    // Vmean = (xsum/512) @ w_v + b_v
    mv2_k<0, 32, 128><<<g1, 256, 0, stream>>>(xpart, w_v, b_v, vfullp, nullptr, 1.f / 512.f, 1024, 1024);
    // y0 = Vmean @ w_o + b_o
    mv2_k<0, 8, 128><<<g1, 256, 0, stream>>>(vfullp, w_o, b_o, y0p, nullptr, 1.f, 1024, 1024);
    // quantum layer 0   (y = y0)
    mv2_k<0, 8, 128><<<g1, 256, 0, stream>>>(y0p, aw1, ab1, t0p, nullptr, 1.f, 1024, 1024);
    mv2_k<1, 8, 128><<<g1, 256, 0, stream>>>(t0p, aw2, ab2, a0p, nullptr, 1.f, 1024, 1024);
    mv2_k<3, 8, 128><<<g1, 256, 0, stream>>>(a0p, pw1, pb1, s0p, vqc, 1.f, 1024, 1024);
    mv2_k<2, 8, 128><<<g1, 256, 0, stream>>>(s0p, pw2, pb2, h0p, nullptr, 1.f, 1024, 1024);
    // quantum layer 1   (y = y0 + h0 -> NP=16 from yparts base)
    mv2_k<0, 16, 128><<<g1, 256, 0, stream>>>(yparts, aw1 + DDm, ab1 + 1024, t0p, nullptr, 1.f, 1024, 1024);
    mv2_k<1, 8, 128><<<g1, 256, 0, stream>>>(t0p, aw2 + DDm, ab2 + 1024, a0p, nullptr, 1.f, 1024, 1024);
    mv2_k<3, 8, 128><<<g1, 256, 0, stream>>>(a0p, pw1 + DDm, pb1 + 1024, s0p, vqc + 4096, 1.f, 1024, 1024);
    mv2_k<2, 8, 128><<<g1, 256, 0, stream>>>(s0p, pw2 + DDm, pb2 + 1024, h1p, nullptr, 1.f, 1024, 1024);
    // memory encoder first matmul (y = y0+h0+h1 -> NP=24)
    mv2_k<0, 24, 128><<<g1, 256, 0, stream>>>(yparts, mew1, meb1, maccp, nullptr, 1.f, 1024, 1024);
    // mq, top-3 retrieval, comb = [y, mem_ctx]
    mem_k<<<8, 256, 0, stream>>>(maccp, mew2, meb2, mst, rw1, rb1, rw2, rb2, yparts, comb);
    // bridge MLP
    mv2_k<0, 1, 256><<<dim3(64, 8), 256, 0, stream>>>(comb, brw1, brb1, hbap, nullptr, 1.f, 2048, 2048);
    mv2_k<2, 8, 256><<<dim3(32, 8), 256, 0, stream>>>(hbap, brw2, brb2, hbccp, nullptr, 1.f, 2048, 1024);
    // fused layernorm + broadcast to (B,S,D)
    lnb_k<<<256, 256, 0, stream>>>(hbccp, lnsc, lnof, (float4*)d_out);
}